// Round 1
// baseline (149.502 us; speedup 1.0000x reference)
//
#include <hip/hip_runtime.h>

// cvmm: out[m] = x[m] @ w[sel[m]]
// x: [M,64] f32, sel: [M] i32, w: [8,64,64] f32, out: [M,64] f32
//
// Strategy: memory-bound (129 MiB traffic, ~20.5 us floor @6.3TB/s).
// bf16 MFMA 16x16x32, masked-A per expert (8x MFMA overcompute hides under
// the HBM roofline). B fragments for all 8 experts x 2 k-tiles preloaded in
// 64 VGPRs per wave (one 16-wide n-tile per wave; 4 waves/block cover N=64
// and share x rows via L1). No LDS, no barriers.

typedef __bf16 bf16x8 __attribute__((ext_vector_type(8)));
typedef float floatx4 __attribute__((ext_vector_type(4)));

#define MT_PER_BLOCK 16  // m-tiles (16 rows each) per block

__global__ __launch_bounds__(256, 4) void cvmm_kernel(
    const float* __restrict__ x,
    const int* __restrict__ sel,
    const float* __restrict__ w,
    float* __restrict__ out,
    int M)
{
    const int lane = threadIdx.x & 63;
    const int wave = threadIdx.x >> 6;   // 0..3 -> n-tile
    const int n0   = wave << 4;          // n offset (16 cols per wave)
    const int quad = lane >> 4;          // 0..3
    const int l16  = lane & 15;

    // ---- Preload B fragments: B[k = quad*8+j][n = l16] for each (expert, k-tile)
    // w[e][k][n] at ((e*64 + k)*64 + n); frag j-step moves k by 1 -> stride 64 floats.
    bf16x8 bfrag[8][2];
#pragma unroll
    for (int e = 0; e < 8; ++e) {
#pragma unroll
        for (int t = 0; t < 2; ++t) {
            const float* wp = w + ((e * 64 + t * 32 + quad * 8) * 64) + (n0 + l16);
#pragma unroll
            for (int j = 0; j < 8; ++j) {
                bfrag[e][t][j] = (__bf16)wp[j * 64];
            }
        }
    }

    bf16x8 zf;
#pragma unroll
    for (int j = 0; j < 8; ++j) zf[j] = (__bf16)0.0f;

    const int mt0 = blockIdx.x * MT_PER_BLOCK;

    for (int i = 0; i < MT_PER_BLOCK; ++i) {
        const int m0 = (mt0 + i) << 4;   // 16 token rows per m-tile
        if (m0 >= M) break;

        // per-lane expert id of this lane's A row (m = l16)
        const int s = sel[m0 + l16];

        // ---- A fragments: A[m = l16][k = t*32 + quad*8 + j]
        const float* xp = x + (size_t)(m0 + l16) * 64 + quad * 8;
        floatx4 a0lo = *(const floatx4*)(xp);
        floatx4 a0hi = *(const floatx4*)(xp + 4);
        floatx4 a1lo = *(const floatx4*)(xp + 32);
        floatx4 a1hi = *(const floatx4*)(xp + 36);

        bf16x8 af0, af1;
#pragma unroll
        for (int j = 0; j < 4; ++j) {
            af0[j]     = (__bf16)a0lo[j];
            af0[j + 4] = (__bf16)a0hi[j];
            af1[j]     = (__bf16)a1lo[j];
            af1[j + 4] = (__bf16)a1hi[j];
        }

        floatx4 c = {0.0f, 0.0f, 0.0f, 0.0f};

#pragma unroll
        for (int e = 0; e < 8; ++e) {
            const bool ok = (s == e);
            bf16x8 a0m = ok ? af0 : zf;
            bf16x8 a1m = ok ? af1 : zf;
            c = __builtin_amdgcn_mfma_f32_16x16x32_bf16(a0m, bfrag[e][0], c, 0, 0, 0);
            c = __builtin_amdgcn_mfma_f32_16x16x32_bf16(a1m, bfrag[e][1], c, 0, 0, 0);
        }

        // ---- Store: D[row = quad*4 + r][col = l16]
        float* op = out + (size_t)(m0 + quad * 4) * 64 + n0 + l16;
#pragma unroll
        for (int r = 0; r < 4; ++r) {
            op[(size_t)r * 64] = c[r];
        }
    }
}

extern "C" void kernel_launch(void* const* d_in, const int* in_sizes, int n_in,
                              void* d_out, int out_size, void* d_ws, size_t ws_size,
                              hipStream_t stream) {
    const float* x   = (const float*)d_in[0];
    const int*   sel = (const int*)d_in[1];
    const float* w   = (const float*)d_in[2];
    float*       out = (float*)d_out;

    const int M = in_sizes[0] / 64;               // 262144
    const int mtiles = M / 16;                    // 16384
    const int blocks = (mtiles + MT_PER_BLOCK - 1) / MT_PER_BLOCK;  // 1024

    cvmm_kernel<<<blocks, 256, 0, stream>>>(x, sel, w, out, M);
}